// Round 1
// baseline (617.628 us; speedup 1.0000x reference)
//
#include <hip/hip_runtime.h>
#include <math.h>

#define VOCAB 50257
#define DMEAN 1024
#define DMV   1024
#define BATCH 32
#define SEQLEN 128

// ---------------- GEMM1 (z @ W0), k-split partials ----------------
// grid (4 j-blocks, 8 k-chunks), 256 threads. Each thread owns one output
// column j for all 32 batch rows over a 128-wide k-chunk.
__global__ __launch_bounds__(256) void k1_partial(const float* __restrict__ z,
                                                  const float* __restrict__ W0,
                                                  float* __restrict__ part) {
    int tx = threadIdx.x;
    int j  = blockIdx.x * 256 + tx;
    int k0 = blockIdx.y * 128;
    float acc[BATCH];
#pragma unroll
    for (int r = 0; r < BATCH; ++r) acc[r] = 0.f;
#pragma unroll 4
    for (int k = k0; k < k0 + 128; ++k) {
        float w = W0[k * DMV + j];          // coalesced across tx
#pragma unroll
        for (int r = 0; r < BATCH; ++r)
            acc[r] = fmaf(z[r * DMEAN + k], w, acc[r]);  // z uniform -> s_load
    }
#pragma unroll
    for (int r = 0; r < BATCH; ++r)
        part[(blockIdx.y * BATCH + r) * DMV + j] = acc[r];
}

// combine 8 partials + bias + exact GELU -> h [32][1024]
__global__ __launch_bounds__(256) void k1_combine(const float* __restrict__ part,
                                                  const float* __restrict__ b0,
                                                  float* __restrict__ h) {
    int idx = blockIdx.x * 256 + threadIdx.x;   // 0..32767
    int j = idx & (DMV - 1);
    float s = b0[j];
#pragma unroll
    for (int kb = 0; kb < 8; ++kb) s += part[kb * BATCH * DMV + idx];
    float g = 0.5f * s * (1.f + erff(s * 0.70710678118654752f));
    h[idx] = g;
}

// ---------------- GEMM2 (h @ W1 + b1) -> logits [32][50257] ----------------
// One vocab column per thread; 32 row-accumulators in VGPRs; W1 read once,
// coalesced; h read via wave-uniform addresses (scalar loads).
__global__ __launch_bounds__(256) void k2_gemm(const float* __restrict__ h,
                                               const float* __restrict__ W1,
                                               const float* __restrict__ b1,
                                               float* __restrict__ logits) {
    int n = blockIdx.x * 256 + threadIdx.x;
    if (n >= VOCAB) return;
    float bias = b1[n];
    float acc[BATCH];
#pragma unroll
    for (int r = 0; r < BATCH; ++r) acc[r] = bias;
    const float* w = W1 + n;
#pragma unroll 8
    for (int k = 0; k < DMV; ++k) {
        float wv = w[(size_t)k * VOCAB];    // coalesced across tx
#pragma unroll
        for (int r = 0; r < BATCH; ++r)
            acc[r] = fmaf(h[r * DMV + k], wv, acc[r]);  // h uniform -> s_load
    }
#pragma unroll
    for (int r = 0; r < BATCH; ++r)
        logits[(size_t)r * VOCAB + n] = acc[r];
}

// ---------------- per-row log-softmax + label gather ----------------
__device__ inline float block_reduce(float v, bool do_max, float* red) {
    int tx = threadIdx.x;
#pragma unroll
    for (int off = 32; off > 0; off >>= 1) {
        float o = __shfl_down(v, off, 64);
        v = do_max ? fmaxf(v, o) : (v + o);
    }
    if ((tx & 63) == 0) red[tx >> 6] = v;
    __syncthreads();
    float r0 = red[0], r1 = red[1], r2 = red[2], r3 = red[3];
    float res = do_max ? fmaxf(fmaxf(r0, r1), fmaxf(r2, r3))
                       : (r0 + r1) + (r2 + r3);
    __syncthreads();   // allow red[] reuse
    return res;
}

__global__ __launch_bounds__(256) void k3_row(const float* __restrict__ logits,
                                              const int* __restrict__ labels,
                                              float* __restrict__ rowloss) {
    __shared__ float red[4];
    int r  = blockIdx.x;
    int tx = threadIdx.x;
    const float* row = logits + (size_t)r * VOCAB;

    float m = -INFINITY;
    for (int n = tx; n < VOCAB; n += 256) m = fmaxf(m, row[n]);
    m = block_reduce(m, true, red);

    float s = 0.f;
    for (int n = tx; n < VOCAB; n += 256) s += expf(row[n] - m);
    s = block_reduce(s, false, red);

    float lse = m + logf(s);

    float g = 0.f;
    for (int i = tx; i < SEQLEN; i += 256) g += row[labels[r * SEQLEN + i]];
    g = block_reduce(g, false, red);

    if (tx == 0) rowloss[r] = (float)SEQLEN * lse - g;
}

__global__ void k4_final(const float* __restrict__ rowloss, float* __restrict__ out) {
    int tx = threadIdx.x;
    float v = (tx < BATCH) ? rowloss[tx] : 0.f;
#pragma unroll
    for (int off = 32; off > 0; off >>= 1) v += __shfl_down(v, off, 64);
    if (tx == 0) out[0] = v / (float)(BATCH * SEQLEN);
}

extern "C" void kernel_launch(void* const* d_in, const int* in_sizes, int n_in,
                              void* d_out, int out_size, void* d_ws, size_t ws_size,
                              hipStream_t stream) {
    const float* z      = (const float*)d_in[0];
    const int*   labels = (const int*)  d_in[1];
    const float* W0     = (const float*)d_in[2];
    const float* b0     = (const float*)d_in[3];
    const float* W1     = (const float*)d_in[4];
    const float* b1     = (const float*)d_in[5];
    float* out = (float*)d_out;
    float* ws  = (float*)d_ws;

    float* h       = ws;                              // 32768 floats
    float* part    = ws + 32768;                      // 8*32*1024 = 262144
    float* logits  = ws + 32768 + 262144;             // 32*50257 = 1608224
    float* rowloss = logits + (size_t)BATCH * VOCAB;  // 32

    k1_partial<<<dim3(4, 8), 256, 0, stream>>>(z, W0, part);
    k1_combine<<<128, 256, 0, stream>>>(part, b0, h);
    k2_gemm<<<(VOCAB + 255) / 256, 256, 0, stream>>>(h, W1, b1, logits);
    k3_row<<<BATCH, 256, 0, stream>>>(logits, labels, rowloss);
    k4_final<<<1, 64, 0, stream>>>(rowloss, out);
}

// Round 2
// 205.208 us; speedup vs baseline: 3.0098x; 3.0098x over previous
//
#include <hip/hip_runtime.h>
#include <math.h>

#define VOCAB 50257
#define DMEAN 1024
#define DMV   1024
#define BATCH 32
#define SEQLEN 128
#define NS1 16          // k-split factor for GEMM1
#define NCHUNK 8        // softmax chunks per row
#define CHUNKV 6283     // ceil(VOCAB/NCHUNK)

// ---------------- GEMM1 (z @ W0), k-split partials ----------------
__global__ __launch_bounds__(256) void k1_partial(const float* __restrict__ z,
                                                  const float* __restrict__ W0,
                                                  float* __restrict__ part) {
    int tx = threadIdx.x;
    int j  = blockIdx.x * 256 + tx;
    int k0 = blockIdx.y * (DMEAN / NS1);
    float acc[BATCH];
#pragma unroll
    for (int r = 0; r < BATCH; ++r) acc[r] = 0.f;
#pragma unroll 8
    for (int k = k0; k < k0 + (DMEAN / NS1); ++k) {
        float w = W0[k * DMV + j];          // coalesced across tx
#pragma unroll
        for (int r = 0; r < BATCH; ++r)
            acc[r] = fmaf(z[r * DMEAN + k], w, acc[r]);  // uniform -> s_load
    }
#pragma unroll
    for (int r = 0; r < BATCH; ++r)
        part[(blockIdx.y * BATCH + r) * DMV + j] = acc[r];
}

// combine NS1 partials + bias + exact GELU -> h [32][1024]
__global__ __launch_bounds__(256) void k1_combine(const float* __restrict__ part,
                                                  const float* __restrict__ b0,
                                                  float* __restrict__ h) {
    int idx = blockIdx.x * 256 + threadIdx.x;   // 0..32767
    int j = idx & (DMV - 1);
    float s = b0[j];
#pragma unroll
    for (int kb = 0; kb < NS1; ++kb) s += part[kb * BATCH * DMV + idx];
    float g = 0.5f * s * (1.f + erff(s * 0.70710678118654752f));
    h[idx] = g;
}

// ---------------- GEMM2 k-split: h @ W1 chunk -> partials ----------------
// grid (197, nsplit). One vocab column per thread, 32 row-accumulators.
__global__ __launch_bounds__(256) void k2_part(const float* __restrict__ h,
                                               const float* __restrict__ W1,
                                               float* __restrict__ part2,
                                               int kchunk) {
    int n = blockIdx.x * 256 + threadIdx.x;
    if (n >= VOCAB) return;
    int k0 = blockIdx.y * kchunk;
    float acc[BATCH];
#pragma unroll
    for (int r = 0; r < BATCH; ++r) acc[r] = 0.f;
    const float* w = W1 + n;
#pragma unroll 8
    for (int k = k0; k < k0 + kchunk; ++k) {
        float wv = w[(size_t)k * VOCAB];    // coalesced across tx
#pragma unroll
        for (int r = 0; r < BATCH; ++r)
            acc[r] = fmaf(h[r * DMV + k], wv, acc[r]);  // uniform -> s_load
    }
#pragma unroll
    for (int r = 0; r < BATCH; ++r)
        part2[((size_t)blockIdx.y * BATCH + r) * VOCAB + n] = acc[r];
}

// sum nsplit partials + b1 -> logits, float4-vectorized
__global__ __launch_bounds__(256) void k2_combine(const float* __restrict__ part2,
                                                  const float* __restrict__ b1,
                                                  float* __restrict__ logits,
                                                  int nsplit) {
    const unsigned TOT4 = (unsigned)(BATCH * VOCAB) / 4;   // 402056
    unsigned idx = blockIdx.x * 256 + threadIdx.x;
    if (idx >= TOT4) return;
    float4 s = make_float4(0.f, 0.f, 0.f, 0.f);
    for (int c = 0; c < nsplit; ++c) {
        float4 p = *((const float4*)(part2 + (size_t)c * BATCH * VOCAB) + idx);
        s.x += p.x; s.y += p.y; s.z += p.z; s.w += p.w;
    }
    unsigned base = idx * 4;
    float v[4] = {s.x, s.y, s.z, s.w};
#pragma unroll
    for (int i = 0; i < 4; ++i) {
        unsigned e = base + i;
        unsigned n = e - (e / (unsigned)VOCAB) * (unsigned)VOCAB;
        v[i] += b1[n];
    }
    *((float4*)logits + idx) = make_float4(v[0], v[1], v[2], v[3]);
}

// ---------------- split log-softmax ----------------
__device__ inline float block_reduce(float v, bool do_max, float* red) {
    int tx = threadIdx.x;
#pragma unroll
    for (int off = 32; off > 0; off >>= 1) {
        float o = __shfl_down(v, off, 64);
        v = do_max ? fmaxf(v, o) : (v + o);
    }
    if ((tx & 63) == 0) red[tx >> 6] = v;
    __syncthreads();
    float r0 = red[0], r1 = red[1], r2 = red[2], r3 = red[3];
    float res = do_max ? fmaxf(fmaxf(r0, r1), fmaxf(r2, r3))
                       : (r0 + r1) + (r2 + r3);
    __syncthreads();
    return res;
}

// grid (32 rows, NCHUNK chunks): per-chunk max + sumexp
__global__ __launch_bounds__(256) void k3_part(const float* __restrict__ logits,
                                               float* __restrict__ mpart,
                                               float* __restrict__ spart) {
    __shared__ float red[4];
    int r = blockIdx.x, c = blockIdx.y, tx = threadIdx.x;
    int n0 = c * CHUNKV;
    int n1 = min(n0 + CHUNKV, VOCAB);
    const float* row = logits + (size_t)r * VOCAB;

    float m = -INFINITY;
    for (int n = n0 + tx; n < n1; n += 256) m = fmaxf(m, row[n]);
    m = block_reduce(m, true, red);

    float s = 0.f;
    for (int n = n0 + tx; n < n1; n += 256) s += expf(row[n] - m);
    s = block_reduce(s, false, red);

    if (tx == 0) { mpart[r * NCHUNK + c] = m; spart[r * NCHUNK + c] = s; }
}

// combine chunk stats -> lse per row; gather labels; mean
__global__ __launch_bounds__(256) void k3_final(const float* __restrict__ logits,
                                                const int* __restrict__ labels,
                                                const float* __restrict__ mpart,
                                                const float* __restrict__ spart,
                                                float* __restrict__ out) {
    __shared__ float lse_sh[BATCH];
    __shared__ float red[4];
    int tx = threadIdx.x;
    if (tx < BATCH) {
        float M = -INFINITY;
#pragma unroll
        for (int c = 0; c < NCHUNK; ++c) M = fmaxf(M, mpart[tx * NCHUNK + c]);
        float S = 0.f;
#pragma unroll
        for (int c = 0; c < NCHUNK; ++c)
            S += spart[tx * NCHUNK + c] * expf(mpart[tx * NCHUNK + c] - M);
        lse_sh[tx] = M + logf(S);
    }
    __syncthreads();
    float g = 0.f;
    for (int i = tx; i < BATCH * SEQLEN; i += 256) {
        int r = i >> 7;   // SEQLEN = 128
        g += lse_sh[r] - logits[(size_t)r * VOCAB + labels[i]];
    }
    g = block_reduce(g, false, red);
    if (tx == 0) out[0] = g / (float)(BATCH * SEQLEN);
}

extern "C" void kernel_launch(void* const* d_in, const int* in_sizes, int n_in,
                              void* d_out, int out_size, void* d_ws, size_t ws_size,
                              hipStream_t stream) {
    const float* z      = (const float*)d_in[0];
    const int*   labels = (const int*)  d_in[1];
    const float* W0     = (const float*)d_in[2];
    const float* b0     = (const float*)d_in[3];
    const float* W1     = (const float*)d_in[4];
    const float* b1     = (const float*)d_in[5];
    float* out = (float*)d_out;
    float* ws  = (float*)d_ws;

    const size_t LOGN = (size_t)BATCH * VOCAB;            // 1,608,224
    float* h       = ws;                                  // 32768
    float* part1   = h + (size_t)BATCH * DMV;             // NS1*32*1024 = 524288
    float* logits  = part1 + (size_t)NS1 * BATCH * DMV;
    float* part2   = logits + LOGN;
    // choose largest k-split for GEMM2 that fits the workspace
    int nsplit = 8;
    while (nsplit > 1) {
        size_t need = ((size_t)(part2 - ws) + (size_t)nsplit * LOGN + 512) * 4;
        if (need <= ws_size) break;
        nsplit >>= 1;
    }
    float* mpart   = part2 + (size_t)nsplit * LOGN;
    float* spart   = mpart + BATCH * NCHUNK;

    int kchunk = DMV / nsplit;

    k1_partial<<<dim3(4, NS1), 256, 0, stream>>>(z, W0, part1);
    k1_combine<<<(BATCH * DMV) / 256, 256, 0, stream>>>(part1, b0, h);
    k2_part<<<dim3((VOCAB + 255) / 256, nsplit), 256, 0, stream>>>(h, W1, part2, kchunk);
    k2_combine<<<(unsigned)(LOGN / 4 + 255) / 256, 256, 0, stream>>>(part2, b1, logits, nsplit);
    k3_part<<<dim3(BATCH, NCHUNK), 256, 0, stream>>>(logits, mpart, spart);
    k3_final<<<1, 256, 0, stream>>>(logits, labels, mpart, spart, out);
}

// Round 3
// 87.021 us; speedup vs baseline: 7.0974x; 2.3581x over previous
//
#include <hip/hip_runtime.h>
#include <math.h>

#define VOCAB 50257
#define DMEAN 1024
#define DMV   1024
#define BATCH 32
#define SEQLEN 128
#define NS1 32          // k-split for GEMM1
#define NS2 8           // k-split for GEMM2
#define NCHUNK 16       // softmax chunks per row
#define CHUNKV 3142     // ceil(VOCAB/NCHUNK)

// ---------------- GEMM1 (z @ W0), k-split partials ----------------
__global__ __launch_bounds__(256) void k1_partial(const float* __restrict__ z,
                                                  const float* __restrict__ W0,
                                                  float* __restrict__ part) {
    int tx = threadIdx.x;
    int j  = blockIdx.x * 256 + tx;
    int k0 = blockIdx.y * (DMEAN / NS1);
    float acc[BATCH];
#pragma unroll
    for (int r = 0; r < BATCH; ++r) acc[r] = 0.f;
#pragma unroll 8
    for (int k = k0; k < k0 + (DMEAN / NS1); ++k) {
        float w = W0[k * DMV + j];          // coalesced across tx
#pragma unroll
        for (int r = 0; r < BATCH; ++r)
            acc[r] = fmaf(z[r * DMEAN + k], w, acc[r]);
    }
#pragma unroll
    for (int r = 0; r < BATCH; ++r)
        part[(blockIdx.y * BATCH + r) * DMV + j] = acc[r];
}

// combine NS1 partials + bias + exact GELU -> hT [DMV][BATCH] (transposed!)
__global__ __launch_bounds__(256) void k1_combine(const float* __restrict__ part,
                                                  const float* __restrict__ b0,
                                                  float* __restrict__ hT) {
    int idx = blockIdx.x * 256 + threadIdx.x;   // 0..32767, idx = r*DMV + j
    int j = idx & (DMV - 1);
    int r = idx >> 10;
    float s = b0[j];
#pragma unroll
    for (int kb = 0; kb < NS1; ++kb) s += part[kb * BATCH * DMV + idx];
    float g = 0.5f * s * (1.f + erff(s * 0.70710678118654752f));
    hT[j * BATCH + r] = g;
}

// ---------------- GEMM2 k-split: hT-broadcast, W1 streamed ----------------
// One vocab column per thread; per k: 1 coalesced W1 load (256B/wave) +
// 8 uniform float4 hT loads (contiguous 128B, L1-hot / scalarizable) + 32 FMA.
__global__ __launch_bounds__(256, 6) void k2_part(const float* __restrict__ hT,
                                                  const float* __restrict__ W1,
                                                  float* __restrict__ part2) {
    const int kchunk = DMV / NS2;   // 128
    int tx = threadIdx.x;
    int n = blockIdx.x * 256 + tx;
    int nn = min(n, VOCAB - 1);     // clamp; mask the store instead of diverging
    int k0 = blockIdx.y * kchunk;
    float acc[BATCH];
#pragma unroll
    for (int r = 0; r < BATCH; ++r) acc[r] = 0.f;
    const float*  w  = W1 + (size_t)k0 * VOCAB + nn;
    const float4* hp = (const float4*)(hT + (size_t)k0 * BATCH);
#pragma unroll 2
    for (int k = 0; k < kchunk; ++k) {
        float wv = *w; w += VOCAB;
        float4 h4[8];
#pragma unroll
        for (int q = 0; q < 8; ++q) h4[q] = hp[q];   // uniform, offset-folded
        hp += 8;
        const float* hv = (const float*)h4;
#pragma unroll
        for (int r = 0; r < BATCH; ++r)
            acc[r] = fmaf(hv[r], wv, acc[r]);
    }
    if (n < VOCAB) {
        float* p = part2 + (size_t)blockIdx.y * BATCH * VOCAB + n;
#pragma unroll
        for (int r = 0; r < BATCH; ++r) p[(size_t)r * VOCAB] = acc[r];
    }
}

// ---------------- reductions ----------------
__device__ inline float block_reduce(float v, bool do_max, float* red) {
    int tx = threadIdx.x;
#pragma unroll
    for (int off = 32; off > 0; off >>= 1) {
        float o = __shfl_down(v, off, 64);
        v = do_max ? fmaxf(v, o) : (v + o);
    }
    if ((tx & 63) == 0) red[tx >> 6] = v;
    __syncthreads();
    float r0 = red[0], r1 = red[1], r2 = red[2], r3 = red[3];
    float res = do_max ? fmaxf(fmaxf(r0, r1), fmaxf(r2, r3))
                       : (r0 + r1) + (r2 + r3);
    __syncthreads();
    return res;
}

// grid (32 rows, NCHUNK chunks): sum NS2 partials + b1 -> chunk logits in LDS,
// chunk max + sumexp, gather in-range labels. logits never hit global memory.
__global__ __launch_bounds__(256) void k3_fused(const float* __restrict__ part2,
                                                const float* __restrict__ b1,
                                                const int* __restrict__ labels,
                                                float* __restrict__ mpart,
                                                float* __restrict__ spart,
                                                float* __restrict__ gpart) {
    __shared__ float lds[CHUNKV];
    __shared__ float red[4];
    int r = blockIdx.x, c = blockIdx.y, tx = threadIdx.x;
    int n0 = c * CHUNKV;
    int n1 = min(n0 + CHUNKV, VOCAB);

    float m = -INFINITY;
    for (int n = n0 + tx; n < n1; n += 256) {
        float s = b1[n];
#pragma unroll
        for (int cs = 0; cs < NS2; ++cs)
            s += part2[((size_t)cs * BATCH + r) * VOCAB + n];
        lds[n - n0] = s;
        m = fmaxf(m, s);
    }
    m = block_reduce(m, true, red);

    float se = 0.f;
    for (int n = n0 + tx; n < n1; n += 256) se += expf(lds[n - n0] - m);
    se = block_reduce(se, false, red);

    float g = 0.f;
    if (tx < SEQLEN) {
        int lab = labels[r * SEQLEN + tx];
        if (lab >= n0 && lab < n1) g = lds[lab - n0];
    }
    g = block_reduce(g, false, red);

    if (tx == 0) {
        mpart[r * NCHUNK + c] = m;
        spart[r * NCHUNK + c] = se;
        gpart[r * NCHUNK + c] = g;
    }
}

// combine chunk stats -> loss
__global__ __launch_bounds__(64) void k4_final(const float* __restrict__ mpart,
                                               const float* __restrict__ spart,
                                               const float* __restrict__ gpart,
                                               float* __restrict__ out) {
    int tx = threadIdx.x;
    float v = 0.f;
    if (tx < BATCH) {
        float M = -INFINITY;
#pragma unroll
        for (int c = 0; c < NCHUNK; ++c) M = fmaxf(M, mpart[tx * NCHUNK + c]);
        float S = 0.f, G = 0.f;
#pragma unroll
        for (int c = 0; c < NCHUNK; ++c) {
            S += spart[tx * NCHUNK + c] * expf(mpart[tx * NCHUNK + c] - M);
            G += gpart[tx * NCHUNK + c];
        }
        v = (float)SEQLEN * (M + logf(S)) - G;
    }
#pragma unroll
    for (int off = 32; off > 0; off >>= 1) v += __shfl_down(v, off, 64);
    if (tx == 0) out[0] = v / (float)(BATCH * SEQLEN);
}

extern "C" void kernel_launch(void* const* d_in, const int* in_sizes, int n_in,
                              void* d_out, int out_size, void* d_ws, size_t ws_size,
                              hipStream_t stream) {
    const float* z      = (const float*)d_in[0];
    const int*   labels = (const int*)  d_in[1];
    const float* W0     = (const float*)d_in[2];
    const float* b0     = (const float*)d_in[3];
    const float* W1     = (const float*)d_in[4];
    const float* b1     = (const float*)d_in[5];
    float* out = (float*)d_out;
    float* ws  = (float*)d_ws;

    float* part1 = ws;                                    // NS1*32*1024 = 1,048,576
    float* hT    = part1 + (size_t)NS1 * BATCH * DMV;     // 32768
    float* part2 = hT + (size_t)DMV * BATCH;              // NS2*32*VOCAB = 12,865,792
    float* mpart = part2 + (size_t)NS2 * BATCH * VOCAB;   // 512
    float* spart = mpart + BATCH * NCHUNK;                // 512
    float* gpart = spart + BATCH * NCHUNK;                // 512

    k1_partial<<<dim3(4, NS1), 256, 0, stream>>>(z, W0, part1);
    k1_combine<<<(BATCH * DMV) / 256, 256, 0, stream>>>(part1, b0, hT);
    k2_part<<<dim3((VOCAB + 255) / 256, NS2), 256, 0, stream>>>(hT, W1, part2);
    k3_fused<<<dim3(BATCH, NCHUNK), 256, 0, stream>>>(part2, b1, labels, mpart, spart, gpart);
    k4_final<<<1, 64, 0, stream>>>(mpart, spart, gpart, out);
}